// Round 5
// baseline (231.692 us; speedup 1.0000x reference)
//
#include <hip/hip_runtime.h>
#include <stdint.h>

#define S 128
#define R 256
#define CM 256
#define CZ 128
#define H 8
#define D 32

typedef __attribute__((ext_vector_type(8))) short short8;
typedef __attribute__((ext_vector_type(4))) float f32x4;
typedef unsigned short u16;

// ---------- helpers ----------
__device__ __forceinline__ float wsum(float v) {
#pragma unroll
  for (int o = 32; o > 0; o >>= 1) v += __shfl_xor(v, o, 64);
  return v;
}
__device__ __forceinline__ u16 f2bb(float f) {
  unsigned u = __float_as_uint(f);
  return (u16)((u + 0x7fffu + ((u >> 16) & 1u)) >> 16);
}
__device__ __forceinline__ float b2f(u16 u) {
  return __uint_as_float(((unsigned)u) << 16);
}
__device__ __forceinline__ void gl_lds16(const u16* g, u16* l) {
  __builtin_amdgcn_global_load_lds(
      (const __attribute__((address_space(1))) unsigned int*)g,
      (__attribute__((address_space(3))) unsigned int*)l, 16, 0, 0);
}

// stage a [128 rows][64 cols] bf16 tile (src row stride 256 elems) into linear LDS.
__device__ __forceinline__ void stage_tile(const u16* __restrict__ src, u16* lbase,
                                           int w, int l) {
#pragma unroll
  for (int it = 0; it < 4; it++) {
    int rbase = it * 32 + w * 8;
    int row = rbase + (l >> 3);
    int gc8 = (l & 7) ^ (row & 7);
    gl_lds16(src + (size_t)row * 256 + gc8 * 8, lbase + rbase * 64);
  }
}

// ---------- kernel 0: weights -> bf16, transposed [hd'][c]; qscale folded ----------
__global__ __launch_bounds__(256) void k_prep(const float* __restrict__ wq,
                                              const float* __restrict__ wk,
                                              const float* __restrict__ wv,
                                              const float* __restrict__ wg,
                                              const float* __restrict__ wo,
                                              u16* __restrict__ wcat_t,
                                              u16* __restrict__ wot) {
  __shared__ float t[64][65];
  int mat = blockIdx.y;  // 0..4
  const float* src = (mat == 0) ? wq : (mat == 1) ? wk : (mat == 2) ? wv
                     : (mat == 3) ? wg : wo;
  float scale = (mat == 0) ? 0.17677669529663687f : 1.0f;  // 1/sqrt(D) into wq
  u16* dst = (mat < 4) ? (wcat_t + mat * 256 * 256) : wot;
  int ti = blockIdx.x >> 2, tj = blockIdx.x & 3;
  int tid = threadIdx.x;
  int cc = tid & 63, rr4 = tid >> 6;
#pragma unroll
  for (int it = 0; it < 16; it++) {
    int ic = it * 4 + rr4;
    t[ic][cc] = src[(tj * 64 + ic) * 256 + ti * 64 + cc];
  }
  __syncthreads();
#pragma unroll
  for (int it = 0; it < 16; it++) {
    int oh = it * 4 + rr4;
    dst[(ti * 64 + oh) * 256 + tj * 64 + cc] = f2bb(t[cc][oh] * scale);
  }
}

// ---------- kernel 1: pair bias -> bf16  zbb[h][pair] ----------
// 8 lanes per pair; lane owns 16 channels {i*32 + cg*4 .. +3 : i=0..3}.
__global__ __launch_bounds__(256) void k_zbias(const float* __restrict__ z,
                                               const float* __restrict__ lng,
                                               const float* __restrict__ lnb,
                                               const float* __restrict__ wz,
                                               u16* __restrict__ zbb) {
  int tid = threadIdx.x;
  int l = tid & 63, w = tid >> 6;
  int psub = l >> 3, cg = l & 7;
  int pair = blockIdx.x * 32 + w * 8 + psub;
  const float* zr = z + (size_t)pair * CZ;
  float4 v[4];
#pragma unroll
  for (int i = 0; i < 4; i++) v[i] = *(const float4*)(zr + i * 32 + cg * 4);
  float sum = 0.f, ssq = 0.f;
#pragma unroll
  for (int i = 0; i < 4; i++) {
    sum += v[i].x + v[i].y + v[i].z + v[i].w;
    ssq += v[i].x * v[i].x + v[i].y * v[i].y + v[i].z * v[i].z + v[i].w * v[i].w;
  }
  sum += __shfl_xor(sum, 1, 64); sum += __shfl_xor(sum, 2, 64); sum += __shfl_xor(sum, 4, 64);
  ssq += __shfl_xor(ssq, 1, 64); ssq += __shfl_xor(ssq, 2, 64); ssq += __shfl_xor(ssq, 4, 64);
  float mu = sum * (1.0f / CZ);
  float rs = rsqrtf(ssq * (1.0f / CZ) - mu * mu + 1e-5f);
  float ph[8];
#pragma unroll
  for (int hh = 0; hh < 8; hh++) ph[hh] = 0.f;
#pragma unroll
  for (int i = 0; i < 4; i++) {
    int c0 = i * 32 + cg * 4;
    float4 gg = *(const float4*)(lng + c0);
    float4 bb = *(const float4*)(lnb + c0);
    float n0 = (v[i].x - mu) * rs * gg.x + bb.x;
    float n1 = (v[i].y - mu) * rs * gg.y + bb.y;
    float n2 = (v[i].z - mu) * rs * gg.z + bb.z;
    float n3 = (v[i].w - mu) * rs * gg.w + bb.w;
#pragma unroll
    for (int jj = 0; jj < 4; jj++) {
      float nj = (jj == 0) ? n0 : (jj == 1) ? n1 : (jj == 2) ? n2 : n3;
      float4 w0 = *(const float4*)(wz + (c0 + jj) * 8);
      float4 w1 = *(const float4*)(wz + (c0 + jj) * 8 + 4);
      ph[0] = fmaf(nj, w0.x, ph[0]); ph[1] = fmaf(nj, w0.y, ph[1]);
      ph[2] = fmaf(nj, w0.z, ph[2]); ph[3] = fmaf(nj, w0.w, ph[3]);
      ph[4] = fmaf(nj, w1.x, ph[4]); ph[5] = fmaf(nj, w1.y, ph[5]);
      ph[6] = fmaf(nj, w1.z, ph[6]); ph[7] = fmaf(nj, w1.w, ph[7]);
    }
  }
  // component-splitting reduce over the 8 lanes of the pair (xor 1,2,4)
  float a[4];
#pragma unroll
  for (int j = 0; j < 4; j++) {
    float keep = (l & 1) ? ph[4 + j] : ph[j];
    float send = (l & 1) ? ph[j] : ph[4 + j];
    a[j] = keep + __shfl_xor(send, 1, 64);
  }
  float b2[2];
#pragma unroll
  for (int j = 0; j < 2; j++) {
    float keep = (l & 2) ? a[2 + j] : a[j];
    float send = (l & 2) ? a[j] : a[2 + j];
    b2[j] = keep + __shfl_xor(send, 2, 64);
  }
  float keep = (l & 4) ? b2[1] : b2[0];
  float send = (l & 4) ? b2[0] : b2[1];
  float c = keep + __shfl_xor(send, 4, 64);
  int hh = 4 * (l & 1) + (l & 2) + ((l & 4) >> 2);
  zbb[(size_t)hh * 65536 + pair] = f2bb(c);
}

// ---------- kernel 2: LN(m) -> bf16 ----------
__global__ __launch_bounds__(256) void k_lnm(const float* __restrict__ m,
                                             const float* __restrict__ g,
                                             const float* __restrict__ b,
                                             u16* __restrict__ mln) {
  int w = threadIdx.x >> 6, lane = threadIdx.x & 63;
  size_t row = (size_t)blockIdx.x * 4 + w;
  const float4 v = *(const float4*)(m + row * 256 + lane * 4);
  float sum = wsum(v.x + v.y + v.z + v.w);
  float ssq = wsum(v.x * v.x + v.y * v.y + v.z * v.z + v.w * v.w);
  float mu = sum * (1.f / 256);
  float rs = rsqrtf(ssq * (1.f / 256) - mu * mu + 1e-5f);
  const float4 gg = *(const float4*)(g + lane * 4);
  const float4 bb = *(const float4*)(b + lane * 4);
  ushort4 o;
  o.x = f2bb((v.x - mu) * rs * gg.x + bb.x);
  o.y = f2bb((v.y - mu) * rs * gg.y + bb.y);
  o.z = f2bb((v.z - mu) * rs * gg.z + bb.z);
  o.w = f2bb((v.w - mu) * rs * gg.w + bb.w);
  *(ushort4*)(mln + row * 256 + lane * 4) = o;
}

// ---------- kernel 3: 128x128-tile MFMA GEMM  mln @ Wcat -> q/k/vt/g ----------
__global__ __launch_bounds__(256) void k_proj(const u16* __restrict__ mln,
                                              const u16* __restrict__ wcat_t,
                                              const float* __restrict__ bg,
                                              u16* __restrict__ qb,
                                              u16* __restrict__ kbuf,
                                              u16* __restrict__ vt,
                                              u16* __restrict__ gb) {
  __shared__ __align__(16) u16 lds[4 * 8192];  // A0 A1 B0 B1 (16KB each)
  int tid = threadIdx.x;
  int w = tid >> 6, l = tid & 63;
  int l15 = l & 15, lg = l >> 4;
  int wr = w >> 1, wc = w & 1;
  int grow0 = blockIdx.x * 128;
  int hdt0 = blockIdx.y * 128;
  const u16* asrc = mln + (size_t)grow0 * 256;
  const u16* bsrc = wcat_t + (size_t)hdt0 * 256;

  stage_tile(asrc, lds, w, l);
  stage_tile(bsrc, lds + 16384, w, l);
  __syncthreads();

  f32x4 acc[4][4];
#pragma unroll
  for (int mi = 0; mi < 4; mi++)
#pragma unroll
    for (int ni = 0; ni < 4; ni++) acc[mi][ni] = (f32x4){0.f, 0.f, 0.f, 0.f};

#pragma unroll
  for (int kt = 0; kt < 4; kt++) {
    if (kt < 3) {
      stage_tile(asrc + (kt + 1) * 64, lds + ((kt + 1) & 1) * 8192, w, l);
      stage_tile(bsrc + (kt + 1) * 64, lds + 16384 + ((kt + 1) & 1) * 8192, w, l);
    }
    const u16* Ab = lds + (kt & 1) * 8192;
    const u16* Bb = lds + 16384 + (kt & 1) * 8192;
#pragma unroll
    for (int ks = 0; ks < 2; ks++) {
      short8 af[4], bf[4];
#pragma unroll
      for (int i = 0; i < 4; i++) {
        int ra = wr * 64 + i * 16 + l15;
        af[i] = *(const short8*)(Ab + ra * 64 + (((ks * 4 + lg) ^ (ra & 7)) << 3));
        int rb = wc * 64 + i * 16 + l15;
        bf[i] = *(const short8*)(Bb + rb * 64 + (((ks * 4 + lg) ^ (rb & 7)) << 3));
      }
#pragma unroll
      for (int mi = 0; mi < 4; mi++)
#pragma unroll
        for (int ni = 0; ni < 4; ni++)
          acc[mi][ni] =
              __builtin_amdgcn_mfma_f32_16x16x32_bf16(af[mi], bf[ni], acc[mi][ni], 0, 0, 0);
    }
    __syncthreads();
  }

  // ---- epilogue: re-stage through LDS for coalesced uint4 stores ----
  int by = blockIdx.y;
  int mat = by >> 1;            // 0:q 1:k 2:v(transposed) 3:g
  int s = grow0 >> 8, r0 = grow0 & 255;
  int hbase = (by & 1) * 128;
  u16* stg = lds;               // [128][136] bf16

  if (mat == 2) {
#pragma unroll
    for (int mi = 0; mi < 4; mi++)
#pragma unroll
      for (int ni = 0; ni < 4; ni++)
#pragma unroll
        for (int j = 0; j < 4; j++) {
          int rl = wr * 64 + mi * 16 + lg * 4 + j;
          int hl = wc * 64 + ni * 16 + l15;
          stg[hl * 136 + rl] = f2bb(acc[mi][ni][j]);
        }
    __syncthreads();
#pragma unroll
    for (int it = 0; it < 8; it++) {
      int idx = it * 256 + tid;
      int dl = idx >> 4, c = idx & 15;
      int hd = hbase + dl;
      uint4 val = *(const uint4*)(stg + dl * 136 + c * 8);
      *(uint4*)(vt + ((size_t)(s * 8 + (hd >> 5)) * 32 + (hd & 31)) * 256 + r0 + c * 8) = val;
    }
  } else {
    float bgv[4];
    if (mat == 3) {
#pragma unroll
      for (int ni = 0; ni < 4; ni++) bgv[ni] = bg[hbase + wc * 64 + ni * 16 + l15];
    }
#pragma unroll
    for (int mi = 0; mi < 4; mi++)
#pragma unroll
      for (int ni = 0; ni < 4; ni++)
#pragma unroll
        for (int j = 0; j < 4; j++) {
          int rl = wr * 64 + mi * 16 + lg * 4 + j;
          int hl = wc * 64 + ni * 16 + l15;
          float v = acc[mi][ni][j];
          if (mat == 3) v = 1.0f / (1.0f + __expf(-(v + bgv[ni])));
          stg[rl * 136 + hl] = f2bb(v);
        }
    __syncthreads();
#pragma unroll
    for (int it = 0; it < 8; it++) {
      int idx = it * 256 + tid;
      int rl = idx >> 4, c = idx & 15;
      uint4 val = *(const uint4*)(stg + rl * 136 + c * 8);
      int hd = hbase + c * 8;
      if (mat == 3) {
        *(uint4*)(gb + (size_t)(grow0 + rl) * 256 + hd) = val;
      } else {
        u16* dst = (mat == 0) ? qb : kbuf;
        *(uint4*)(dst + ((size_t)(s * 8 + (hd >> 5)) * 256 + r0 + rl) * 32 + (hd & 31)) = val;
      }
    }
  }
}

// ---------- kernel 4: MFMA flash attention per (s,h) with LDS K/V staging ----------
__global__ __launch_bounds__(256) void k_attn(const u16* __restrict__ qb,
                                              const u16* __restrict__ kbuf,
                                              const u16* __restrict__ vt,
                                              const u16* __restrict__ gb,
                                              const u16* __restrict__ zbb,
                                              const float* __restrict__ mask,
                                              u16* __restrict__ og) {
  __shared__ __align__(16) u16 P_l[4][64 * 72];  // per-wave, 36,864 B
  __shared__ __align__(16) u16 K_l[2][64 * 32];  // 4 KB each, swizzled slots
  __shared__ __align__(16) u16 V_l[2][32 * 64];  // 4 KB each, swizzled slots
  int blk = blockIdx.x;
  int s = blk >> 3, h = blk & 7;
  int tid = threadIdx.x, w = tid >> 6, l = tid & 63;
  int l15 = l & 15, lg = l >> 4;
  int q0 = w * 64;
  size_t base = (size_t)(s * 8 + h) * 256 * 32;

  // ---- staging geometry (wave-uniform LDS base + per-lane global src) ----
  // K: wave w covers rows w*16..+15; lane: row = w*16+(l>>3... (l>>2), c16=l&3
  int krow_l = w * 16 + (l >> 2);
  int kslot = (l & 3) ^ ((krow_l >> 1) & 3);
  const u16* ksrc0 = kbuf + base + (size_t)krow_l * 32 + kslot * 8;
  // V: wave w covers d rows w*8..+7; lane: d = w*8+(l>>3), r16 = l&7
  int vd_l = w * 8 + (l >> 3);
  int vslot = (l & 7) ^ (vd_l & 7);
  const u16* vsrc0 = vt + base + (size_t)vd_l * 256 + vslot * 8;

#define STAGE(kb, buf)                                            \
  {                                                               \
    gl_lds16(ksrc0 + (kb) * 64 * 32, &K_l[buf][0] + w * 512);     \
    gl_lds16(vsrc0 + (kb) * 64, &V_l[buf][0] + w * 512);          \
  }

  STAGE(0, 0);

  short8 qm[4];
#pragma unroll
  for (int mi = 0; mi < 4; mi++)
    qm[mi] = *(const short8*)(qb + base + (size_t)(q0 + mi * 16 + l15) * 32 + lg * 8);
  const u16* zrow = zbb + (size_t)h * 65536;
  const float* mrow = mask + s * 256;
  f32x4 oacc[4][2];
  float lsum[4][4];
#pragma unroll
  for (int mi = 0; mi < 4; mi++) {
#pragma unroll
    for (int n = 0; n < 2; n++) oacc[mi][n] = (f32x4){0.f, 0.f, 0.f, 0.f};
#pragma unroll
    for (int j = 0; j < 4; j++) lsum[mi][j] = 0.f;
  }
  u16* Pw = P_l[w];
  __syncthreads();  // stage(0) complete

#pragma unroll
  for (int kb4 = 0; kb4 < 4; kb4++) {
    int cur = kb4 & 1;
    if (kb4 < 3) STAGE(kb4 + 1, cur ^ 1);
    // prefetch zb (bf16) + mask for this key block
    u16 z16[4][4];   // [mi][ni] per j handled below: load 16 scalars
    float mv[4];
#pragma unroll
    for (int ni = 0; ni < 4; ni++) mv[ni] = mrow[kb4 * 64 + ni * 16 + l15];
    // ---- QK^T from LDS K ----
    f32x4 sc[4][4];
#pragma unroll
    for (int ni = 0; ni < 4; ni++) {
      int row_l = ni * 16 + l15;
      short8 kf = *(const short8*)(&K_l[cur][0] + row_l * 32 + ((lg ^ ((row_l >> 1) & 3)) << 3));
#pragma unroll
      for (int mi = 0; mi < 4; mi++)
        sc[mi][ni] = __builtin_amdgcn_mfma_f32_16x16x32_bf16(
            qm[mi], kf, (f32x4){0.f, 0.f, 0.f, 0.f}, 0, 0, 0);
    }
    // ---- bias + exp + P write + partial row-sum ----
#pragma unroll
    for (int mi = 0; mi < 4; mi++) {
#pragma unroll
      for (int j = 0; j < 4; j++) {
        int rowq = q0 + mi * 16 + lg * 4 + j;
        const u16* zq = zrow + (size_t)rowq * 256 + kb4 * 64;
#pragma unroll
        for (int ni = 0; ni < 4; ni++) z16[ni][j & 3] = zq[ni * 16 + l15];  // reuse slot
#pragma unroll
        for (int ni = 0; ni < 4; ni++) {
          float sv = sc[mi][ni][j] + b2f(z16[ni][j & 3]) + 1e9f * (mv[ni] - 1.0f);
          float p = __expf(sv);
          lsum[mi][j] += p;
          Pw[(mi * 16 + lg * 4 + j) * 72 + ni * 16 + l15] = f2bb(p);
        }
      }
    }
    // ---- P @ V from LDS V ----
#pragma unroll
    for (int ks = 0; ks < 2; ks++) {
#pragma unroll
      for (int n2 = 0; n2 < 2; n2++) {
        int d = n2 * 16 + l15;
        short8 vf = *(const short8*)(&V_l[cur][0] + d * 64 + (((ks * 4 + lg) ^ (d & 7)) << 3));
#pragma unroll
        for (int mi = 0; mi < 4; mi++) {
          short8 pa = *(const short8*)((char*)Pw + (mi * 16 + l15) * 144 + ks * 64 + lg * 16);
          oacc[mi][n2] = __builtin_amdgcn_mfma_f32_16x16x32_bf16(pa, vf, oacc[mi][n2], 0, 0, 0);
        }
      }
    }
    __syncthreads();  // drain stage(kb4+1) + finish LDS reads before overwrite
  }
#pragma unroll
  for (int mi = 0; mi < 4; mi++) {
#pragma unroll
    for (int j = 0; j < 4; j++) {
      float v = lsum[mi][j];
      v += __shfl_xor(v, 1, 64);
      v += __shfl_xor(v, 2, 64);
      v += __shfl_xor(v, 4, 64);
      v += __shfl_xor(v, 8, 64);
      lsum[mi][j] = v;
    }
  }
#pragma unroll
  for (int mi = 0; mi < 4; mi++) {
#pragma unroll
    for (int j = 0; j < 4; j++) {
      float inv = 1.0f / lsum[mi][j];
      int rowq = q0 + mi * 16 + lg * 4 + j;
      size_t ob = ((size_t)s * 256 + rowq) * 256 + h * 32;
#pragma unroll
      for (int n2 = 0; n2 < 2; n2++) {
        int d = n2 * 16 + l15;
        float gv = b2f(gb[ob + d]);
        og[ob + d] = f2bb(oacc[mi][n2][j] * inv * gv);
      }
    }
  }
#undef STAGE
}

// ---------- kernel 5: 128x128-tile MFMA GEMM  og @ WO + bo -> out f32 ----------
__global__ __launch_bounds__(256) void k_out(const u16* __restrict__ og,
                                             const u16* __restrict__ wot,
                                             const float* __restrict__ bo,
                                             float* __restrict__ out) {
  __shared__ __align__(16) u16 lds[4 * 8192];
  int tid = threadIdx.x;
  int w = tid >> 6, l = tid & 63;
  int l15 = l & 15, lg = l >> 4;
  int wr = w >> 1, wc = w & 1;
  int grow0 = blockIdx.x * 128;
  int ct0 = blockIdx.y * 128;
  const u16* asrc = og + (size_t)grow0 * 256;
  const u16* bsrc = wot + (size_t)ct0 * 256;

  stage_tile(asrc, lds, w, l);
  stage_tile(bsrc, lds + 16384, w, l);
  __syncthreads();

  f32x4 acc[4][4];
#pragma unroll
  for (int mi = 0; mi < 4; mi++)
#pragma unroll
    for (int ni = 0; ni < 4; ni++) acc[mi][ni] = (f32x4){0.f, 0.f, 0.f, 0.f};

#pragma unroll
  for (int kt = 0; kt < 4; kt++) {
    if (kt < 3) {
      stage_tile(asrc + (kt + 1) * 64, lds + ((kt + 1) & 1) * 8192, w, l);
      stage_tile(bsrc + (kt + 1) * 64, lds + 16384 + ((kt + 1) & 1) * 8192, w, l);
    }
    const u16* Ab = lds + (kt & 1) * 8192;
    const u16* Bb = lds + 16384 + (kt & 1) * 8192;
#pragma unroll
    for (int ks = 0; ks < 2; ks++) {
      short8 af[4], bf[4];
#pragma unroll
      for (int i = 0; i < 4; i++) {
        int ra = wr * 64 + i * 16 + l15;
        af[i] = *(const short8*)(Ab + ra * 64 + (((ks * 4 + lg) ^ (ra & 7)) << 3));
        int rb = wc * 64 + i * 16 + l15;
        bf[i] = *(const short8*)(Bb + rb * 64 + (((ks * 4 + lg) ^ (rb & 7)) << 3));
      }
#pragma unroll
      for (int mi = 0; mi < 4; mi++)
#pragma unroll
        for (int ni = 0; ni < 4; ni++)
          acc[mi][ni] =
              __builtin_amdgcn_mfma_f32_16x16x32_bf16(af[mi], bf[ni], acc[mi][ni], 0, 0, 0);
    }
    __syncthreads();
  }

  int cout_base = ct0 + wc * 64;
#pragma unroll
  for (int ni = 0; ni < 4; ni++) {
    int cout = cout_base + ni * 16 + l15;
    float bov = bo[cout];
#pragma unroll
    for (int mi = 0; mi < 4; mi++)
#pragma unroll
      for (int j = 0; j < 4; j++)
        out[(size_t)(grow0 + wr * 64 + mi * 16 + lg * 4 + j) * 256 + cout] =
            acc[mi][ni][j] + bov;
  }
}

extern "C" void kernel_launch(void* const* d_in, const int* in_sizes, int n_in,
                              void* d_out, int out_size, void* d_ws, size_t ws_size,
                              hipStream_t stream) {
  const float* m      = (const float*)d_in[0];
  const float* z      = (const float*)d_in[1];
  const float* mask   = (const float*)d_in[2];
  const float* ln_m_g = (const float*)d_in[3];
  const float* ln_m_b = (const float*)d_in[4];
  const float* ln_z_g = (const float*)d_in[5];
  const float* ln_z_b = (const float*)d_in[6];
  const float* wz     = (const float*)d_in[7];
  const float* wq     = (const float*)d_in[8];
  const float* wk     = (const float*)d_in[9];
  const float* wv     = (const float*)d_in[10];
  const float* wg     = (const float*)d_in[11];
  const float* bg     = (const float*)d_in[12];
  const float* wo     = (const float*)d_in[13];
  const float* bo     = (const float*)d_in[14];
  float* out = (float*)d_out;

  char* ws = (char*)d_ws;
  const size_t MiB = 1u << 20;
  u16* zbb     = (u16*)(ws);                        // 1 MiB  [h][pair] bf16
  u16* wcat_t  = (u16*)(ws + 2 * MiB);              // 512 KiB
  u16* wot     = (u16*)(ws + 2 * MiB + 512 * 1024); // 128 KiB
  u16* mln     = (u16*)(ws + 3 * MiB);              // 16 MiB
  u16* qb      = (u16*)(ws + 19 * MiB);             // 16 MiB  [s][h][r][d]
  u16* kb      = (u16*)(ws + 35 * MiB);             // 16 MiB  [s][h][r][d]
  u16* vt      = (u16*)(ws + 51 * MiB);             // 16 MiB  [s][h][d][r]
  u16* gb      = (u16*)(ws + 67 * MiB);             // 16 MiB  [row][hd]
  u16* ogb     = (u16*)(ws + 83 * MiB);             // 16 MiB  [row][hd]
  (void)in_sizes; (void)n_in; (void)out_size; (void)ws_size;

  k_prep<<<dim3(16, 5), 256, 0, stream>>>(wq, wk, wv, wg, wo, wcat_t, wot);
  k_zbias<<<(R * R) / 32, 256, 0, stream>>>(z, ln_z_g, ln_z_b, wz, zbb);
  k_lnm<<<(S * R) / 4, 256, 0, stream>>>(m, ln_m_g, ln_m_b, mln);
  k_proj<<<dim3(256, 8), 256, 0, stream>>>(mln, wcat_t, bg, qb, kb, vt, gb);
  k_attn<<<S * H, 256, 0, stream>>>(qb, kb, vt, gb, zbb, mask, ogb);
  k_out<<<dim3(256, 2), 256, 0, stream>>>(ogb, wot, bo, out);
}

// Round 6
// 221.325 us; speedup vs baseline: 1.0468x; 1.0468x over previous
//
#include <hip/hip_runtime.h>
#include <stdint.h>

#define S 128
#define R 256
#define CM 256
#define CZ 128
#define H 8
#define D 32

typedef __attribute__((ext_vector_type(8))) short short8;
typedef __attribute__((ext_vector_type(4))) float f32x4;
typedef unsigned short u16;

// ---------- helpers ----------
__device__ __forceinline__ float wsum(float v) {
#pragma unroll
  for (int o = 32; o > 0; o >>= 1) v += __shfl_xor(v, o, 64);
  return v;
}
__device__ __forceinline__ u16 f2bb(float f) {
  unsigned u = __float_as_uint(f);
  return (u16)((u + 0x7fffu + ((u >> 16) & 1u)) >> 16);
}
__device__ __forceinline__ float b2f(u16 u) {
  return __uint_as_float(((unsigned)u) << 16);
}
__device__ __forceinline__ void gl_lds16(const u16* g, u16* l) {
  __builtin_amdgcn_global_load_lds(
      (const __attribute__((address_space(1))) unsigned int*)g,
      (__attribute__((address_space(3))) unsigned int*)l, 16, 0, 0);
}

// stage a [128 rows][64 cols] bf16 tile (src row stride 256 elems) into linear LDS.
__device__ __forceinline__ void stage_tile(const u16* __restrict__ src, u16* lbase,
                                           int w, int l) {
#pragma unroll
  for (int it = 0; it < 4; it++) {
    int rbase = it * 32 + w * 8;
    int row = rbase + (l >> 3);
    int gc8 = (l & 7) ^ (row & 7);
    gl_lds16(src + (size_t)row * 256 + gc8 * 8, lbase + rbase * 64);
  }
}

// ---------- kernel 0: weights -> bf16, transposed [hd'][c]; qscale folded ----------
__global__ __launch_bounds__(256) void k_prep(const float* __restrict__ wq,
                                              const float* __restrict__ wk,
                                              const float* __restrict__ wv,
                                              const float* __restrict__ wg,
                                              const float* __restrict__ wo,
                                              u16* __restrict__ wcat_t,
                                              u16* __restrict__ wot) {
  __shared__ float t[64][65];
  int mat = blockIdx.y;  // 0..4
  const float* src = (mat == 0) ? wq : (mat == 1) ? wk : (mat == 2) ? wv
                     : (mat == 3) ? wg : wo;
  float scale = (mat == 0) ? 0.17677669529663687f : 1.0f;  // 1/sqrt(D) into wq
  u16* dst = (mat < 4) ? (wcat_t + mat * 256 * 256) : wot;
  int ti = blockIdx.x >> 2, tj = blockIdx.x & 3;
  int tid = threadIdx.x;
  int cc = tid & 63, rr4 = tid >> 6;
#pragma unroll
  for (int it = 0; it < 16; it++) {
    int ic = it * 4 + rr4;
    t[ic][cc] = src[(tj * 64 + ic) * 256 + ti * 64 + cc];
  }
  __syncthreads();
#pragma unroll
  for (int it = 0; it < 16; it++) {
    int oh = it * 4 + rr4;
    dst[(ti * 64 + oh) * 256 + tj * 64 + cc] = f2bb(t[cc][oh] * scale);
  }
}

// ---------- kernel 1: pair bias -> bf16 TRANSPOSED  zbb[h][col*256+q] ----------
// op enumerates output slots; q = op & 255 (= z row i), col = op >> 8 (= z col j).
// 8 lanes per pair; lane owns 16 channels {i*32 + cg*4 .. +3 : i=0..3}.
__global__ __launch_bounds__(256) void k_zbias(const float* __restrict__ z,
                                               const float* __restrict__ lng,
                                               const float* __restrict__ lnb,
                                               const float* __restrict__ wz,
                                               u16* __restrict__ zbb) {
  int tid = threadIdx.x;
  int l = tid & 63, w = tid >> 6;
  int psub = l >> 3, cg = l & 7;
  int op = blockIdx.x * 32 + w * 8 + psub;   // output slot (col-major over z)
  int qi = op & 255, cj = op >> 8;
  const float* zr = z + ((size_t)qi * 256 + cj) * CZ;
  float4 v[4];
#pragma unroll
  for (int i = 0; i < 4; i++) v[i] = *(const float4*)(zr + i * 32 + cg * 4);
  float sum = 0.f, ssq = 0.f;
#pragma unroll
  for (int i = 0; i < 4; i++) {
    sum += v[i].x + v[i].y + v[i].z + v[i].w;
    ssq += v[i].x * v[i].x + v[i].y * v[i].y + v[i].z * v[i].z + v[i].w * v[i].w;
  }
  sum += __shfl_xor(sum, 1, 64); sum += __shfl_xor(sum, 2, 64); sum += __shfl_xor(sum, 4, 64);
  ssq += __shfl_xor(ssq, 1, 64); ssq += __shfl_xor(ssq, 2, 64); ssq += __shfl_xor(ssq, 4, 64);
  float mu = sum * (1.0f / CZ);
  float rs = rsqrtf(ssq * (1.0f / CZ) - mu * mu + 1e-5f);
  float ph[8];
#pragma unroll
  for (int hh = 0; hh < 8; hh++) ph[hh] = 0.f;
#pragma unroll
  for (int i = 0; i < 4; i++) {
    int c0 = i * 32 + cg * 4;
    float4 gg = *(const float4*)(lng + c0);
    float4 bb = *(const float4*)(lnb + c0);
    float n0 = (v[i].x - mu) * rs * gg.x + bb.x;
    float n1 = (v[i].y - mu) * rs * gg.y + bb.y;
    float n2 = (v[i].z - mu) * rs * gg.z + bb.z;
    float n3 = (v[i].w - mu) * rs * gg.w + bb.w;
#pragma unroll
    for (int jj = 0; jj < 4; jj++) {
      float nj = (jj == 0) ? n0 : (jj == 1) ? n1 : (jj == 2) ? n2 : n3;
      float4 w0 = *(const float4*)(wz + (c0 + jj) * 8);
      float4 w1 = *(const float4*)(wz + (c0 + jj) * 8 + 4);
      ph[0] = fmaf(nj, w0.x, ph[0]); ph[1] = fmaf(nj, w0.y, ph[1]);
      ph[2] = fmaf(nj, w0.z, ph[2]); ph[3] = fmaf(nj, w0.w, ph[3]);
      ph[4] = fmaf(nj, w1.x, ph[4]); ph[5] = fmaf(nj, w1.y, ph[5]);
      ph[6] = fmaf(nj, w1.z, ph[6]); ph[7] = fmaf(nj, w1.w, ph[7]);
    }
  }
  // component-splitting reduce over the 8 lanes of the pair (xor 1,2,4)
  float a[4];
#pragma unroll
  for (int j = 0; j < 4; j++) {
    float keep = (l & 1) ? ph[4 + j] : ph[j];
    float send = (l & 1) ? ph[j] : ph[4 + j];
    a[j] = keep + __shfl_xor(send, 1, 64);
  }
  float b2[2];
#pragma unroll
  for (int j = 0; j < 2; j++) {
    float keep = (l & 2) ? a[2 + j] : a[j];
    float send = (l & 2) ? a[j] : a[2 + j];
    b2[j] = keep + __shfl_xor(send, 2, 64);
  }
  float keep = (l & 4) ? b2[1] : b2[0];
  float send = (l & 4) ? b2[0] : b2[1];
  float c = keep + __shfl_xor(send, 4, 64);
  int hh = 4 * (l & 1) + (l & 2) + ((l & 4) >> 2);
  zbb[(size_t)hh * 65536 + op] = f2bb(c);
}

// ---------- kernel 2: LN(m) -> bf16 ----------
__global__ __launch_bounds__(256) void k_lnm(const float* __restrict__ m,
                                             const float* __restrict__ g,
                                             const float* __restrict__ b,
                                             u16* __restrict__ mln) {
  int w = threadIdx.x >> 6, lane = threadIdx.x & 63;
  size_t row = (size_t)blockIdx.x * 4 + w;
  const float4 v = *(const float4*)(m + row * 256 + lane * 4);
  float sum = wsum(v.x + v.y + v.z + v.w);
  float ssq = wsum(v.x * v.x + v.y * v.y + v.z * v.z + v.w * v.w);
  float mu = sum * (1.f / 256);
  float rs = rsqrtf(ssq * (1.f / 256) - mu * mu + 1e-5f);
  const float4 gg = *(const float4*)(g + lane * 4);
  const float4 bb = *(const float4*)(b + lane * 4);
  ushort4 o;
  o.x = f2bb((v.x - mu) * rs * gg.x + bb.x);
  o.y = f2bb((v.y - mu) * rs * gg.y + bb.y);
  o.z = f2bb((v.z - mu) * rs * gg.z + bb.z);
  o.w = f2bb((v.w - mu) * rs * gg.w + bb.w);
  *(ushort4*)(mln + row * 256 + lane * 4) = o;
}

// ---------- kernel 3: 128x128-tile MFMA GEMM  mln @ Wcat -> q/k/vt/g ----------
__global__ __launch_bounds__(256) void k_proj(const u16* __restrict__ mln,
                                              const u16* __restrict__ wcat_t,
                                              const float* __restrict__ bg,
                                              u16* __restrict__ qb,
                                              u16* __restrict__ kbuf,
                                              u16* __restrict__ vt,
                                              u16* __restrict__ gb) {
  __shared__ __align__(16) u16 lds[4 * 8192];  // A0 A1 B0 B1 (16KB each)
  int tid = threadIdx.x;
  int w = tid >> 6, l = tid & 63;
  int l15 = l & 15, lg = l >> 4;
  int wr = w >> 1, wc = w & 1;
  int grow0 = blockIdx.x * 128;
  int hdt0 = blockIdx.y * 128;
  const u16* asrc = mln + (size_t)grow0 * 256;
  const u16* bsrc = wcat_t + (size_t)hdt0 * 256;

  stage_tile(asrc, lds, w, l);
  stage_tile(bsrc, lds + 16384, w, l);
  __syncthreads();

  f32x4 acc[4][4];
#pragma unroll
  for (int mi = 0; mi < 4; mi++)
#pragma unroll
    for (int ni = 0; ni < 4; ni++) acc[mi][ni] = (f32x4){0.f, 0.f, 0.f, 0.f};

#pragma unroll
  for (int kt = 0; kt < 4; kt++) {
    if (kt < 3) {
      stage_tile(asrc + (kt + 1) * 64, lds + ((kt + 1) & 1) * 8192, w, l);
      stage_tile(bsrc + (kt + 1) * 64, lds + 16384 + ((kt + 1) & 1) * 8192, w, l);
    }
    const u16* Ab = lds + (kt & 1) * 8192;
    const u16* Bb = lds + 16384 + (kt & 1) * 8192;
#pragma unroll
    for (int ks = 0; ks < 2; ks++) {
      short8 af[4], bf[4];
#pragma unroll
      for (int i = 0; i < 4; i++) {
        int ra = wr * 64 + i * 16 + l15;
        af[i] = *(const short8*)(Ab + ra * 64 + (((ks * 4 + lg) ^ (ra & 7)) << 3));
        int rb = wc * 64 + i * 16 + l15;
        bf[i] = *(const short8*)(Bb + rb * 64 + (((ks * 4 + lg) ^ (rb & 7)) << 3));
      }
#pragma unroll
      for (int mi = 0; mi < 4; mi++)
#pragma unroll
        for (int ni = 0; ni < 4; ni++)
          acc[mi][ni] =
              __builtin_amdgcn_mfma_f32_16x16x32_bf16(af[mi], bf[ni], acc[mi][ni], 0, 0, 0);
    }
    __syncthreads();
  }

  // ---- epilogue: re-stage through LDS for coalesced uint4 stores ----
  int by = blockIdx.y;
  int mat = by >> 1;            // 0:q 1:k 2:v(transposed) 3:g
  int s = grow0 >> 8, r0 = grow0 & 255;
  int hbase = (by & 1) * 128;
  u16* stg = lds;               // [128][136] bf16

  if (mat == 2) {
#pragma unroll
    for (int mi = 0; mi < 4; mi++)
#pragma unroll
      for (int ni = 0; ni < 4; ni++)
#pragma unroll
        for (int j = 0; j < 4; j++) {
          int rl = wr * 64 + mi * 16 + lg * 4 + j;
          int hl = wc * 64 + ni * 16 + l15;
          stg[hl * 136 + rl] = f2bb(acc[mi][ni][j]);
        }
    __syncthreads();
#pragma unroll
    for (int it = 0; it < 8; it++) {
      int idx = it * 256 + tid;
      int dl = idx >> 4, c = idx & 15;
      int hd = hbase + dl;
      uint4 val = *(const uint4*)(stg + dl * 136 + c * 8);
      *(uint4*)(vt + ((size_t)(s * 8 + (hd >> 5)) * 32 + (hd & 31)) * 256 + r0 + c * 8) = val;
    }
  } else {
    float bgv[4];
    if (mat == 3) {
#pragma unroll
      for (int ni = 0; ni < 4; ni++) bgv[ni] = bg[hbase + wc * 64 + ni * 16 + l15];
    }
#pragma unroll
    for (int mi = 0; mi < 4; mi++)
#pragma unroll
      for (int ni = 0; ni < 4; ni++)
#pragma unroll
        for (int j = 0; j < 4; j++) {
          int rl = wr * 64 + mi * 16 + lg * 4 + j;
          int hl = wc * 64 + ni * 16 + l15;
          float v = acc[mi][ni][j];
          if (mat == 3) v = 1.0f / (1.0f + __expf(-(v + bgv[ni])));
          stg[rl * 136 + hl] = f2bb(v);
        }
    __syncthreads();
#pragma unroll
    for (int it = 0; it < 8; it++) {
      int idx = it * 256 + tid;
      int rl = idx >> 4, c = idx & 15;
      uint4 val = *(const uint4*)(stg + rl * 136 + c * 8);
      int hd = hbase + c * 8;
      if (mat == 3) {
        *(uint4*)(gb + (size_t)(grow0 + rl) * 256 + hd) = val;
      } else {
        u16* dst = (mat == 0) ? qb : kbuf;
        *(uint4*)(dst + ((size_t)(s * 8 + (hd >> 5)) * 256 + r0 + rl) * 32 + (hd & 31)) = val;
      }
    }
  }
}

// ---------- kernel 4: MFMA flash attention per (s,h), barrier-free ----------
__global__ __launch_bounds__(256) void k_attn(const u16* __restrict__ qb,
                                              const u16* __restrict__ kbuf,
                                              const u16* __restrict__ vt,
                                              const u16* __restrict__ gb,
                                              const u16* __restrict__ zbb,
                                              const float* __restrict__ mask,
                                              u16* __restrict__ og) {
  __shared__ __align__(16) u16 P_l[4][64 * 72];  // per-wave, stride 72 (9x16B)
  int blk = blockIdx.x;
  int s = blk >> 3, h = blk & 7;
  int tid = threadIdx.x, w = tid >> 6, l = tid & 63;
  int l15 = l & 15, lg = l >> 4;
  int q0 = w * 64;
  size_t base = (size_t)(s * 8 + h) * 256 * 32;
  short8 qm[4];
#pragma unroll
  for (int mi = 0; mi < 4; mi++)
    qm[mi] = *(const short8*)(qb + base + (size_t)(q0 + mi * 16 + l15) * 32 + lg * 8);
  const u16* zL = zbb + (size_t)h * 65536;   // [col][q] bf16
  const float* mrow = mask + s * 256;
  f32x4 oacc[4][2];
  float lsum[4][4];
#pragma unroll
  for (int mi = 0; mi < 4; mi++) {
#pragma unroll
    for (int n = 0; n < 2; n++) oacc[mi][n] = (f32x4){0.f, 0.f, 0.f, 0.f};
#pragma unroll
    for (int j = 0; j < 4; j++) lsum[mi][j] = 0.f;
  }
  u16* Pw = P_l[w];
#pragma unroll
  for (int kb4 = 0; kb4 < 4; kb4++) {
    // ---- QK^T ----
    f32x4 sc[4][4];
#pragma unroll
    for (int ni = 0; ni < 4; ni++) {
      short8 kf = *(const short8*)(kbuf + base + (size_t)(kb4 * 64 + ni * 16 + l15) * 32 + lg * 8);
#pragma unroll
      for (int mi = 0; mi < 4; mi++)
        sc[mi][ni] = __builtin_amdgcn_mfma_f32_16x16x32_bf16(
            qm[mi], kf, (f32x4){0.f, 0.f, 0.f, 0.f}, 0, 0, 0);
    }
    // ---- bias + exp + P write + partial row-sum ----
    float mv[4];
#pragma unroll
    for (int ni = 0; ni < 4; ni++)
      mv[ni] = 1e9f * (mrow[kb4 * 64 + ni * 16 + l15] - 1.0f);
#pragma unroll
    for (int mi = 0; mi < 4; mi++) {
      int qb4 = q0 + mi * 16 + lg * 4;
#pragma unroll
      for (int ni = 0; ni < 4; ni++) {
        int col = kb4 * 64 + ni * 16 + l15;
        ushort4 zu = *(const ushort4*)(zL + (size_t)col * 256 + qb4);
#pragma unroll
        for (int j = 0; j < 4; j++) {
          u16 zj = (j == 0) ? zu.x : (j == 1) ? zu.y : (j == 2) ? zu.z : zu.w;
          float sv = sc[mi][ni][j] + b2f(zj) + mv[ni];
          float p = __expf(sv);  // scores O(1): no max subtraction
          lsum[mi][j] += p;
          Pw[(mi * 16 + lg * 4 + j) * 72 + ni * 16 + l15] = f2bb(p);
        }
      }
    }
    // ---- P @ V (B-frags straight from global vt[d][k], L2-resident) ----
#pragma unroll
    for (int ks = 0; ks < 2; ks++) {
#pragma unroll
      for (int n2 = 0; n2 < 2; n2++) {
        short8 vf = *(const short8*)(vt + base + (size_t)(n2 * 16 + l15) * 256 +
                                     kb4 * 64 + ks * 32 + lg * 8);
#pragma unroll
        for (int mi = 0; mi < 4; mi++) {
          short8 pa = *(const short8*)((char*)Pw + (mi * 16 + l15) * 144 + ks * 64 + lg * 16);
          oacc[mi][n2] = __builtin_amdgcn_mfma_f32_16x16x32_bf16(pa, vf, oacc[mi][n2], 0, 0, 0);
        }
      }
    }
  }
#pragma unroll
  for (int mi = 0; mi < 4; mi++) {
#pragma unroll
    for (int j = 0; j < 4; j++) {
      float v = lsum[mi][j];
      v += __shfl_xor(v, 1, 64);
      v += __shfl_xor(v, 2, 64);
      v += __shfl_xor(v, 4, 64);
      v += __shfl_xor(v, 8, 64);
      lsum[mi][j] = v;
    }
  }
#pragma unroll
  for (int mi = 0; mi < 4; mi++) {
#pragma unroll
    for (int j = 0; j < 4; j++) {
      float inv = 1.0f / lsum[mi][j];
      int rowq = q0 + mi * 16 + lg * 4 + j;
      size_t ob = ((size_t)s * 256 + rowq) * 256 + h * 32;
#pragma unroll
      for (int n2 = 0; n2 < 2; n2++) {
        int d = n2 * 16 + l15;
        float gv = b2f(gb[ob + d]);
        og[ob + d] = f2bb(oacc[mi][n2][j] * inv * gv);
      }
    }
  }
}

// ---------- kernel 5: 128x128-tile MFMA GEMM  og @ WO + bo -> out f32 ----------
__global__ __launch_bounds__(256) void k_out(const u16* __restrict__ og,
                                             const u16* __restrict__ wot,
                                             const float* __restrict__ bo,
                                             float* __restrict__ out) {
  __shared__ __align__(16) u16 lds[4 * 8192];
  int tid = threadIdx.x;
  int w = tid >> 6, l = tid & 63;
  int l15 = l & 15, lg = l >> 4;
  int wr = w >> 1, wc = w & 1;
  int grow0 = blockIdx.x * 128;
  int ct0 = blockIdx.y * 128;
  const u16* asrc = og + (size_t)grow0 * 256;
  const u16* bsrc = wot + (size_t)ct0 * 256;

  stage_tile(asrc, lds, w, l);
  stage_tile(bsrc, lds + 16384, w, l);
  __syncthreads();

  f32x4 acc[4][4];
#pragma unroll
  for (int mi = 0; mi < 4; mi++)
#pragma unroll
    for (int ni = 0; ni < 4; ni++) acc[mi][ni] = (f32x4){0.f, 0.f, 0.f, 0.f};

#pragma unroll
  for (int kt = 0; kt < 4; kt++) {
    if (kt < 3) {
      stage_tile(asrc + (kt + 1) * 64, lds + ((kt + 1) & 1) * 8192, w, l);
      stage_tile(bsrc + (kt + 1) * 64, lds + 16384 + ((kt + 1) & 1) * 8192, w, l);
    }
    const u16* Ab = lds + (kt & 1) * 8192;
    const u16* Bb = lds + 16384 + (kt & 1) * 8192;
#pragma unroll
    for (int ks = 0; ks < 2; ks++) {
      short8 af[4], bf[4];
#pragma unroll
      for (int i = 0; i < 4; i++) {
        int ra = wr * 64 + i * 16 + l15;
        af[i] = *(const short8*)(Ab + ra * 64 + (((ks * 4 + lg) ^ (ra & 7)) << 3));
        int rb = wc * 64 + i * 16 + l15;
        bf[i] = *(const short8*)(Bb + rb * 64 + (((ks * 4 + lg) ^ (rb & 7)) << 3));
      }
#pragma unroll
      for (int mi = 0; mi < 4; mi++)
#pragma unroll
        for (int ni = 0; ni < 4; ni++)
          acc[mi][ni] =
              __builtin_amdgcn_mfma_f32_16x16x32_bf16(af[mi], bf[ni], acc[mi][ni], 0, 0, 0);
    }
    __syncthreads();
  }

  int cout_base = ct0 + wc * 64;
#pragma unroll
  for (int ni = 0; ni < 4; ni++) {
    int cout = cout_base + ni * 16 + l15;
    float bov = bo[cout];
#pragma unroll
    for (int mi = 0; mi < 4; mi++)
#pragma unroll
      for (int j = 0; j < 4; j++)
        out[(size_t)(grow0 + wr * 64 + mi * 16 + lg * 4 + j) * 256 + cout] =
            acc[mi][ni][j] + bov;
  }
}

extern "C" void kernel_launch(void* const* d_in, const int* in_sizes, int n_in,
                              void* d_out, int out_size, void* d_ws, size_t ws_size,
                              hipStream_t stream) {
  const float* m      = (const float*)d_in[0];
  const float* z      = (const float*)d_in[1];
  const float* mask   = (const float*)d_in[2];
  const float* ln_m_g = (const float*)d_in[3];
  const float* ln_m_b = (const float*)d_in[4];
  const float* ln_z_g = (const float*)d_in[5];
  const float* ln_z_b = (const float*)d_in[6];
  const float* wz     = (const float*)d_in[7];
  const float* wq     = (const float*)d_in[8];
  const float* wk     = (const float*)d_in[9];
  const float* wv     = (const float*)d_in[10];
  const float* wg     = (const float*)d_in[11];
  const float* bg     = (const float*)d_in[12];
  const float* wo     = (const float*)d_in[13];
  const float* bo     = (const float*)d_in[14];
  float* out = (float*)d_out;

  char* ws = (char*)d_ws;
  const size_t MiB = 1u << 20;
  u16* zbb     = (u16*)(ws);                        // 1 MiB  [h][col*256+q] bf16
  u16* wcat_t  = (u16*)(ws + 2 * MiB);              // 512 KiB
  u16* wot     = (u16*)(ws + 2 * MiB + 512 * 1024); // 128 KiB
  u16* mln     = (u16*)(ws + 3 * MiB);              // 16 MiB
  u16* qb      = (u16*)(ws + 19 * MiB);             // 16 MiB  [s][h][r][d]
  u16* kb      = (u16*)(ws + 35 * MiB);             // 16 MiB  [s][h][r][d]
  u16* vt      = (u16*)(ws + 51 * MiB);             // 16 MiB  [s][h][d][r]
  u16* gb      = (u16*)(ws + 67 * MiB);             // 16 MiB  [row][hd]
  u16* ogb     = (u16*)(ws + 83 * MiB);             // 16 MiB  [row][hd]
  (void)in_sizes; (void)n_in; (void)out_size; (void)ws_size;

  k_prep<<<dim3(16, 5), 256, 0, stream>>>(wq, wk, wv, wg, wo, wcat_t, wot);
  k_zbias<<<(R * R) / 32, 256, 0, stream>>>(z, ln_z_g, ln_z_b, wz, zbb);
  k_lnm<<<(S * R) / 4, 256, 0, stream>>>(m, ln_m_g, ln_m_b, mln);
  k_proj<<<dim3(256, 8), 256, 0, stream>>>(mln, wcat_t, bg, qb, kb, vt, gb);
  k_attn<<<S * H, 256, 0, stream>>>(qb, kb, vt, gb, zbb, mask, ogb);
  k_out<<<dim3(256, 2), 256, 0, stream>>>(ogb, wot, bo, out);
}